// Round 1
// baseline (1647.261 us; speedup 1.0000x reference)
//
#include <hip/hip_runtime.h>

// MLA forward, MI355X gfx950. Round 3.
// H=128 DN=128 DR=64 DV=128 RQ=1536 RKV=512 HSZ=5120 S=1024
//
// Changes vs round 2 (1618.5 us):
//  - k_gemm256: 256x256 tile, BK=64, 8-wave, 8-phase schedule with counted
//    vmcnt(6) fences (T3+T4), st_16x32 LDS XOR swizzle via inverse-swizzled
//    global source + swizzled ds_read (T2, rule 21), s_setprio around MFMA
//    clusters (T5), XCD-aware block swizzle (T1). Used for q-up, kv-up and
//    out-proj (split-K x4). Replaces the m97 128^2 structure for these.
//  - k_attn: XOR bank-swizzle on Ks / Vs / Ps (write and read sides use the
//    identical mapping) to kill the 8..16-way ds_read_b128 conflicts.
//  - q-down / kv-down keep the proven 128^2 k_gemm_bt (small share of time).

typedef __attribute__((ext_vector_type(8))) short short8;
typedef __attribute__((ext_vector_type(4))) float f32x4;
typedef unsigned short u16;

__device__ __forceinline__ u16 f2bf(float f) {
  union { float f; unsigned u; } v; v.f = f;
  unsigned r = v.u + 0x7fffu + ((v.u >> 16) & 1u);   // RNE
  return (u16)(r >> 16);
}
__device__ __forceinline__ float bf2f(u16 s) {
  union { unsigned u; float f; } v; v.u = ((unsigned)s) << 16; return v.f;
}

__device__ __forceinline__ void gl_lds16(const u16* g, u16* l) {
  __builtin_amdgcn_global_load_lds(
      (const __attribute__((address_space(1))) void*)g,
      (__attribute__((address_space(3))) void*)l,
      16, 0, 0);
}

#define BARX()  asm volatile("s_barrier" ::: "memory")
#define LGKM0() do { asm volatile("s_waitcnt lgkmcnt(0)" ::: "memory"); \
                     __builtin_amdgcn_sched_barrier(0); } while (0)
#define VMW(n)  asm volatile("s_waitcnt vmcnt(" #n ")" ::: "memory")

// ---------------------------------------------------------------- zero fill
__global__ void k_zero(float* __restrict__ p, int n4) {
  int i = blockIdx.x * 256 + threadIdx.x;
  if (i < n4) ((float4*)p)[i] = make_float4(0.f, 0.f, 0.f, 0.f);
}

// ---------------------------------------------------------------- cast
__global__ void k_cast(const float* __restrict__ in, u16* __restrict__ out, int n4) {
  int i = blockIdx.x * 256 + threadIdx.x;
  if (i < n4) {
    float4 v = ((const float4*)in)[i];
    ushort4 o;
    o.x = f2bf(v.x); o.y = f2bf(v.y); o.z = f2bf(v.z); o.w = f2bf(v.w);
    ((ushort4*)out)[i] = o;
  }
}

// ---------------------------------------------------------------- weight cast+transpose
// W fp32 [K][N] -> WT bf16 [Npad][K]; pad rows (n>=N) zeroed.
__global__ void k_wt(const float* __restrict__ W, u16* __restrict__ WT,
                     int K, int N) {
  __shared__ u16 t[32][33];
  int n0 = blockIdx.x * 32, k0 = blockIdx.y * 32;
  int tx = threadIdx.x, ty = threadIdx.y;   // 32 x 8
#pragma unroll
  for (int r = 0; r < 4; r++) {
    int kl = ty + r * 8, n = n0 + tx;
    float v = (n < N) ? W[(size_t)(k0 + kl) * N + n] : 0.f;
    t[kl][tx] = f2bf(v);
  }
  __syncthreads();
#pragma unroll
  for (int r = 0; r < 4; r++) {
    int nl = ty + r * 8;
    WT[(size_t)(n0 + nl) * K + k0 + tx] = t[tx][nl];
  }
}

// ---------------------------------------------------------------- GEMM 128^2 (m97 structure)
// kept for the small split-K down-projections.
template<int OUT_MODE>   // 0 fp32, 1 bf16, 2 fp32 atomicAdd
__global__ __launch_bounds__(256) void k_gemm_bt(
    const u16* __restrict__ A, const u16* __restrict__ BT,
    void* __restrict__ Cv, int M, int N, int K, int kChunk)
{
  __shared__ u16 As[128 * 32];
  __shared__ u16 Bs[128 * 32];
  const int tid = threadIdx.x;
  const int wave = tid >> 6, lane = tid & 63;
  const int qd = lane >> 4, l = lane & 15;
  const int bn0 = blockIdx.x * 128, bm0 = blockIdx.y * 128;
  const int k0 = blockIdx.z * kChunk;
  const int wrow = (wave >> 1) * 64, wcol = (wave & 1) * 64;
  const f32x4 fzero = {0.f, 0.f, 0.f, 0.f};

  f32x4 acc[4][4];
#pragma unroll
  for (int i = 0; i < 4; i++)
#pragma unroll
    for (int j = 0; j < 4; j++) acc[i][j] = fzero;

  const int sm = wave * 16 + (lane >> 2);
  const int sc = (lane & 3) * 8;
  const u16* a0 = A  + (size_t)(bm0 + sm) * K + sc;
  const u16* a1 = A  + (size_t)(bm0 + 64 + sm) * K + sc;
  const u16* b0 = BT + (size_t)(bn0 + sm) * K + sc;
  const u16* b1 = BT + (size_t)(bn0 + 64 + sm) * K + sc;
  u16* aD0 = As + wave * 512;
  u16* aD1 = As + 2048 + wave * 512;
  u16* bD0 = Bs + wave * 512;
  u16* bD1 = Bs + 2048 + wave * 512;

  const int kEnd = k0 + kChunk;
  for (int kt = k0; kt < kEnd; kt += 32) {
    gl_lds16(a0 + kt, aD0);
    gl_lds16(a1 + kt, aD1);
    gl_lds16(b0 + kt, bD0);
    gl_lds16(b1 + kt, bD1);
    __syncthreads();

    short8 af[4], bfr[4];
#pragma unroll
    for (int i = 0; i < 4; i++) af[i]  = *(const short8*)&As[(wrow + i * 16 + l) * 32 + qd * 8];
#pragma unroll
    for (int j = 0; j < 4; j++) bfr[j] = *(const short8*)&Bs[(wcol + j * 16 + l) * 32 + qd * 8];
#pragma unroll
    for (int i = 0; i < 4; i++)
#pragma unroll
      for (int j = 0; j < 4; j++)
        acc[i][j] = __builtin_amdgcn_mfma_f32_16x16x32_bf16(af[i], bfr[j], acc[i][j], 0, 0, 0);
    __syncthreads();
  }

#pragma unroll
  for (int i = 0; i < 4; i++) {
    int r = bm0 + wrow + i * 16 + qd * 4;
#pragma unroll
    for (int j = 0; j < 4; j++) {
      int c = bn0 + wcol + j * 16 + l;
      if (c < N) {
#pragma unroll
        for (int reg = 0; reg < 4; ++reg) {
          if (OUT_MODE == 1)
            ((u16*)Cv)[(size_t)(r + reg) * N + c] = f2bf(acc[i][j][reg]);
          else if (OUT_MODE == 0)
            ((float*)Cv)[(size_t)(r + reg) * N + c] = acc[i][j][reg];
          else
            atomicAdd(&((float*)Cv)[(size_t)(r + reg) * N + c], acc[i][j][reg]);
        }
      }
    }
  }
}

// ---------------------------------------------------------------- GEMM 256^2, 8-phase
// C[M,N] = A[M,K] @ BT[N,K], bf16 in. 512 threads = 8 waves (2M x 4N); per-wave
// C 128x64 (8x4 fragments of 16x16x32). BK=64, two K-tiles per iteration.
// LDS: 2 dbuf x (256x64) x {A,B} x bf16 = 128 KiB.
// st_16x32 swizzle: flip 32-byte (16-u16) group bit when (row&4); applied as
// inverse swizzle on the global source of global_load_lds (linear LDS dest) and
// as forward swizzle on ds_read addresses (both are the same XOR involution).
// Pipeline (per iteration j; tiles t0=2j buf0, t1=2j+1 buf1; stages of tile T
// always occur >=3 stage-slots before the vmcnt(6) fence preceding T's reads):
//   ph1: ds A-mh0 + B-nh0 (12); stage t1.A1            ; MFMA Q(0,0)
//   ph2: ds B-nh1 (4)                                  ; MFMA Q(0,1)
//   ph3: ds A-mh1 (8);         stage t2.B0 t2.B1       ; MFMA Q(1,1)
//   ph4:                       stage t2.A0; vmcnt(6)   ; MFMA Q(1,0)
//   ph5..ph8: same on buf1 with stages t2.A1 / t3.B0 t3.B1 / t3.A0; vmcnt(6)
// Region safety: each LDS half is staged >=1 phase after its last ds_read.
template<int OUT_MODE>   // 1 bf16 store, 2 fp32 atomicAdd (split-K)
__global__ __launch_bounds__(512, 2) void k_gemm256(
    const u16* __restrict__ A, const u16* __restrict__ BT, void* __restrict__ Cv,
    int M, int N, int K, int kChunk)
{
  __shared__ u16 As[2][16384];   // per buf: 256 rows x 64 cols bf16 (32 KB)
  __shared__ u16 Bs[2][16384];
  const int tid = threadIdx.x;
  const int w = tid >> 6, lane = tid & 63;
  const int wm = w >> 2, wn = w & 3;
  const int qd = lane >> 4, l = lane & 15;

  // T1: XCD-aware swizzle. All launch grids have nwg % 8 == 0.
  const int gx = gridDim.x, gy = gridDim.y;
  const int nwg = gx * gy * gridDim.z;
  int lin = blockIdx.x + gx * (blockIdx.y + gy * blockIdx.z);
  int lin2 = (lin & 7) * (nwg >> 3) + (lin >> 3);
  const int bx = lin2 % gx;
  const int byz = lin2 / gx;
  const int bm0 = (byz % gy) * 256;
  const int bn0 = bx * 256;
  const int k0  = (byz / gy) * kChunk;
  const int ntiles = kChunk >> 6;        // even, >= 2
  const int niter  = ntiles >> 1;

  f32x4 acc[8][4];
  const f32x4 fz = {0.f, 0.f, 0.f, 0.f};
#pragma unroll
  for (int i = 0; i < 8; i++)
#pragma unroll
    for (int j = 0; j < 4; j++) acc[i][j] = fz;

// stage one 128-row half-tile (hf) of K-tile tI from matP (rows rb..rb+255,
// row stride K) into dstB. Linear LDS dest (wave-uniform base), source column
// inverse-swizzled so that swizzled ds_reads see the right data.
#define STG(matP, rb, tI, hf, dstB)                                           \
  {                                                                           \
    const int _kt = k0 + (tI) * 64;                                           \
    _Pragma("unroll")                                                         \
    for (int _L = 0; _L < 2; ++_L) {                                          \
      const int _ob = (hf) * 8192 + _L * 4096 + w * 512;   /* u16, uniform */ \
      const int _o  = _ob + lane * 8;                                         \
      const int _r  = _o >> 6;                                                \
      const int _c  = (_o & 63) ^ ((_r & 4) << 2);                            \
      gl_lds16((matP) + (size_t)((rb) + _r) * K + _kt + _c, (dstB) + _ob);    \
    }                                                                         \
  }

#define LDA4(buf, mh)                                                         \
  _Pragma("unroll")                                                           \
  for (int _i = 0; _i < 4; ++_i) {                                            \
    const int _row = wm * 128 + (mh) * 64 + _i * 16 + l;                      \
    const int _sw = (_row & 4) << 2;                                          \
    af[_i][0] = *(const short8*)&(buf)[_row * 64 + ((qd * 8) ^ _sw)];         \
    af[_i][1] = *(const short8*)&(buf)[_row * 64 + ((32 + qd * 8) ^ _sw)];    \
  }

#define LDB2(buf, nh, dst)                                                    \
  _Pragma("unroll")                                                           \
  for (int _j = 0; _j < 2; ++_j) {                                            \
    const int _row = wn * 64 + (nh) * 32 + _j * 16 + l;                       \
    const int _sw = (_row & 4) << 2;                                          \
    dst[_j][0] = *(const short8*)&(buf)[_row * 64 + ((qd * 8) ^ _sw)];        \
    dst[_j][1] = *(const short8*)&(buf)[_row * 64 + ((32 + qd * 8) ^ _sw)];   \
  }

#define MFQ(mh, nh, bsrc)                                                     \
  __builtin_amdgcn_s_setprio(1);                                              \
  _Pragma("unroll")                                                           \
  for (int _i = 0; _i < 4; ++_i)                                              \
    _Pragma("unroll")                                                         \
    for (int _j = 0; _j < 2; ++_j) {                                          \
      f32x4 _a = acc[(mh) * 4 + _i][(nh) * 2 + _j];                           \
      _a = __builtin_amdgcn_mfma_f32_16x16x32_bf16(af[_i][0], bsrc[_j][0], _a, 0, 0, 0); \
      _a = __builtin_amdgcn_mfma_f32_16x16x32_bf16(af[_i][1], bsrc[_j][1], _a, 0, 0, 0); \
      acc[(mh) * 4 + _i][(nh) * 2 + _j] = _a;                                 \
    }                                                                         \
  __builtin_amdgcn_s_setprio(0);

  // prologue: tile0 fully + tile1 {B0,B1,A0}; tile1.A1 goes at ph1 of j=0.
  STG(BT, bn0, 0, 0, Bs[0]); STG(BT, bn0, 0, 1, Bs[0]);
  STG(A,  bm0, 0, 0, As[0]); STG(A,  bm0, 0, 1, As[0]);
  STG(BT, bn0, 1, 0, Bs[1]); STG(BT, bn0, 1, 1, Bs[1]);
  STG(A,  bm0, 1, 0, As[1]);
  VMW(6);            // tile0's 8 loads (oldest) retired
  BARX();

  short8 af[4][2], bf0[2][2], bf1[2][2];
  for (int j = 0; j < niter; ++j) {
    int t2 = 2 * j + 2; if (t2 >= ntiles) t2 -= ntiles;   // wrap: redundant stage, safe
    int t3 = t2 + 1;

    // ---- tile 2j (buf0) ----
    LDA4(As[0], 0); LDB2(Bs[0], 0, bf0);                 // ph1
    STG(A, bm0, 2 * j + 1, 1, As[1]);
    BARX(); LGKM0();
    MFQ(0, 0, bf0);
    BARX();

    LDB2(Bs[0], 1, bf1);                                 // ph2
    BARX(); LGKM0();
    MFQ(0, 1, bf1);
    BARX();

    LDA4(As[0], 1);                                      // ph3
    STG(BT, bn0, t2, 0, Bs[0]); STG(BT, bn0, t2, 1, Bs[0]);
    BARX(); LGKM0();
    MFQ(1, 1, bf1);
    BARX();

    STG(A, bm0, t2, 0, As[0]);                           // ph4
    VMW(6);                                              // tile 2j+1 fully retired
    BARX(); LGKM0();
    MFQ(1, 0, bf0);
    BARX();

    // ---- tile 2j+1 (buf1) ----
    LDA4(As[1], 0); LDB2(Bs[1], 0, bf0);                 // ph5
    STG(A, bm0, t2, 1, As[0]);
    BARX(); LGKM0();
    MFQ(0, 0, bf0);
    BARX();

    LDB2(Bs[1], 1, bf1);                                 // ph6
    BARX(); LGKM0();
    MFQ(0, 1, bf1);
    BARX();

    LDA4(As[1], 1);                                      // ph7
    STG(BT, bn0, t3, 0, Bs[1]); STG(BT, bn0, t3, 1, Bs[1]);
    BARX(); LGKM0();
    MFQ(1, 1, bf1);
    BARX();

    STG(A, bm0, t3, 0, As[1]);                           // ph8
    VMW(6);                                              // tile 2j+2 fully retired
    BARX(); LGKM0();
    MFQ(1, 0, bf0);
    BARX();
  }
  asm volatile("s_waitcnt vmcnt(0)" ::: "memory");

#undef STG
#undef LDA4
#undef LDB2
#undef MFQ

  // epilogue: C/D layout col=lane&15, row=(lane>>4)*4+reg
#pragma unroll
  for (int i = 0; i < 8; ++i) {
    int r = bm0 + wm * 128 + i * 16 + qd * 4;
#pragma unroll
    for (int jj = 0; jj < 4; ++jj) {
      int c = bn0 + wn * 64 + jj * 16 + l;
#pragma unroll
      for (int reg = 0; reg < 4; ++reg) {
        if (OUT_MODE == 1)
          ((u16*)Cv)[(size_t)(r + reg) * N + c] = f2bf(acc[i][jj][reg]);
        else
          atomicAdd(&((float*)Cv)[(size_t)(r + reg) * N + c], acc[i][jj][reg]);
      }
    }
  }
}

// ---------------------------------------------------------------- rmsnorm
__global__ void k_rmsnorm(const float* __restrict__ in, int istride, int W,
                          const float* __restrict__ w, u16* __restrict__ out) {
  int row = blockIdx.x, tid = threadIdx.x;
  const float* x = in + (size_t)row * istride;
  float s = 0.f;
  for (int i = tid; i < W; i += 256) { float v = x[i]; s += v * v; }
#pragma unroll
  for (int o = 32; o; o >>= 1) s += __shfl_xor(s, o);
  __shared__ float red[4];
  if ((tid & 63) == 0) red[tid >> 6] = s;
  __syncthreads();
  float tot = red[0] + red[1] + red[2] + red[3];
  float sc = rsqrtf(tot / (float)W + 1e-6f);
  for (int i = tid; i < W; i += 256)
    out[(size_t)row * W + i] = f2bf(x[i] * sc * w[i]);
}

// ---------------------------------------------------------------- rope
__global__ void k_rope_q(u16* __restrict__ q) {   // in-place on (1024, 128*192)
  int idx = blockIdx.x * 256 + threadIdx.x;       // 1024*128*32
  int s = idx >> 12, r = idx & 4095, h = r >> 5, i = r & 31;
  float inv = expf((float)i * (-logf(10000.f) / 32.f));
  float ang = (float)s * inv, sn, cs;
  sincosf(ang, &sn, &cs);
  u16* p1 = q + (size_t)s * 24576 + h * 192 + 128 + i;
  u16* p2 = p1 + 32;
  float x1 = bf2f(*p1), x2 = bf2f(*p2);
  *p1 = f2bf(x1 * cs - x2 * sn);
  *p2 = f2bf(x2 * cs + x1 * sn);
}

__global__ void k_rope_k(const float* __restrict__ ckv, u16* __restrict__ kr) {
  int idx = blockIdx.x * 256 + threadIdx.x;       // 1024*32
  int s = idx >> 5, i = idx & 31;
  float inv = expf((float)i * (-logf(10000.f) / 32.f));
  float ang = (float)s * inv, sn, cs;
  sincosf(ang, &sn, &cs);
  const float* src = ckv + (size_t)s * 576 + 512;
  float x1 = src[i], x2 = src[i + 32];
  kr[s * 64 + i]      = f2bf(x1 * cs - x2 * sn);
  kr[s * 64 + 32 + i] = f2bf(x2 * cs + x1 * sn);
}

// ---------------------------------------------------------------- V transpose
__global__ void k_transpose_v(const u16* __restrict__ kv, u16* __restrict__ vt) {
  __shared__ u16 tile[32][33];
  int h = blockIdx.z, s0 = blockIdx.x * 32, d0 = blockIdx.y * 32;
  int tx = threadIdx.x, ty = threadIdx.y;   // 32 x 8
#pragma unroll
  for (int k2 = 0; k2 < 4; k2++) {
    int r = ty + k2 * 8;
    tile[r][tx] = kv[(size_t)(s0 + r) * 32768 + h * 256 + 128 + d0 + tx];
  }
  __syncthreads();
#pragma unroll
  for (int k2 = 0; k2 < 4; k2++) {
    int r = ty + k2 * 8;
    vt[(size_t)h * 131072 + (size_t)(d0 + r) * 1024 + s0 + tx] = tile[tx][r];
  }
}

// ---------------------------------------------------------------- attention
// One block = (head h, 64 q-rows). 4 waves x 16 q-rows. 16 kv-tiles of 64.
// LDS tiles carry an XOR bank-swizzle at 8-u16 granularity: stored group =
// logical group ^ (row & 7), applied identically on write and read.
__global__ __launch_bounds__(256, 2) void k_attn(
    const u16* __restrict__ q,    // (1024, 128*192)
    const u16* __restrict__ kvn,  // (1024, 128*256): k_nope at h*256+0..127
    const u16* __restrict__ kr,   // (1024, 64) roped k_rope, shared across heads
    const u16* __restrict__ vt,   // (128, 128, 1024) V^T per head
    u16* __restrict__ o)          // (1024, 128*128)
{
  __shared__ u16 Ks[64][200];
  __shared__ u16 Vs[128][72];
  __shared__ u16 Ps[4][16][64];
  const int h = blockIdx.x, q0 = blockIdx.y * 64;
  const int tid = threadIdx.x, wave = tid >> 6, lane = tid & 63;
  const int qd = lane >> 4, l = lane & 15;
  const float scale = 0.07216878364870323f;   // 1/sqrt(192)
  const f32x4 fzero = {0.f, 0.f, 0.f, 0.f};

  short8 qf[6];
  {
    const u16* qp = q + (size_t)(q0 + wave * 16 + l) * 24576 + h * 192 + qd * 8;
#pragma unroll
    for (int kk = 0; kk < 6; kk++) qf[kk] = *(const short8*)(qp + kk * 32);
  }

  f32x4 Of[8];
#pragma unroll
  for (int jt = 0; jt < 8; jt++) Of[jt] = fzero;
  float m_i[4] = {-1e30f, -1e30f, -1e30f, -1e30f};
  float l_i[4] = {0.f, 0.f, 0.f, 0.f};

  for (int kt = 0; kt < 16; ++kt) {
    const int kv0 = kt * 64;
    __syncthreads();
#pragma unroll
    for (int it = 0; it < 6; ++it) {
      int ci = it * 256 + tid;
      int r = ci / 24, c = ci % 24;
      int col0 = c * 8;
      const u16* src = (col0 < 128)
          ? kvn + (size_t)(kv0 + r) * 32768 + h * 256 + col0
          : kr + (size_t)(kv0 + r) * 64 + (col0 - 128);
      *(short8*)&Ks[r][(c ^ (r & 7)) * 8] = *(const short8*)src;
    }
#pragma unroll
    for (int it = 0; it < 4; ++it) {
      int ci = it * 256 + tid;
      int dv = ci >> 3, c = ci & 7;
      *(short8*)&Vs[dv][(c ^ (dv & 7)) * 8] =
          *(const short8*)(vt + (size_t)h * 131072 + (size_t)dv * 1024 + kv0 + c * 8);
    }
    __syncthreads();

    f32x4 sf[4];
#pragma unroll
    for (int j = 0; j < 4; j++) sf[j] = fzero;
#pragma unroll
    for (int kk = 0; kk < 6; kk++)
#pragma unroll
      for (int j = 0; j < 4; j++) {
        short8 bf = *(const short8*)&Ks[j * 16 + l][(((kk * 4 + qd) ^ (l & 7))) * 8];
        sf[j] = __builtin_amdgcn_mfma_f32_16x16x32_bf16(qf[kk], bf, sf[j], 0, 0, 0);
      }
#pragma unroll
    for (int j = 0; j < 4; j++) sf[j] *= scale;

#pragma unroll
    for (int reg = 0; reg < 4; ++reg) {
      float mx = fmaxf(fmaxf(sf[0][reg], sf[1][reg]), fmaxf(sf[2][reg], sf[3][reg]));
#pragma unroll
      for (int off = 1; off < 16; off <<= 1) mx = fmaxf(mx, __shfl_xor(mx, off));
      float mnew = fmaxf(m_i[reg], mx);
      float alpha = expf(m_i[reg] - mnew);
      m_i[reg] = mnew;
      float rs = 0.f;
      int prow = qd * 4 + reg;
#pragma unroll
      for (int j = 0; j < 4; j++) {
        float p = expf(sf[j][reg] - mnew);
        rs += p;
        int g = (j * 2 + (l >> 3)) ^ (prow & 7);
        Ps[wave][prow][g * 8 + (l & 7)] = f2bf(p);
      }
#pragma unroll
      for (int off = 1; off < 16; off <<= 1) rs += __shfl_xor(rs, off);
      l_i[reg] = l_i[reg] * alpha + rs;
#pragma unroll
      for (int jt = 0; jt < 8; jt++) Of[jt][reg] *= alpha;
    }

#pragma unroll
    for (int ks = 0; ks < 2; ++ks) {
      short8 pf = *(const short8*)&Ps[wave][l][(((ks * 4 + qd) ^ (l & 7))) * 8];
#pragma unroll
      for (int jt = 0; jt < 8; jt++) {
        short8 vf = *(const short8*)&Vs[jt * 16 + l][(((ks * 4 + qd) ^ (l & 7))) * 8];
        Of[jt] = __builtin_amdgcn_mfma_f32_16x16x32_bf16(pf, vf, Of[jt], 0, 0, 0);
      }
    }
  }

#pragma unroll
  for (int reg = 0; reg < 4; ++reg) {
    float inv_l = 1.f / l_i[reg];
    int row = q0 + wave * 16 + qd * 4 + reg;
#pragma unroll
    for (int jt = 0; jt < 8; jt++)
      o[(size_t)row * 16384 + h * 128 + jt * 16 + l] = f2bf(Of[jt][reg] * inv_l);
  }
}

// ---------------------------------------------------------------- launch
extern "C" void kernel_launch(void* const* d_in, const int* in_sizes, int n_in,
                              void* d_out, int out_size, void* d_ws, size_t ws_size,
                              hipStream_t stream)
{
  const float* hidden = (const float*)d_in[0];
  const float* Wq_c   = (const float*)d_in[1];
  const float* q_nw   = (const float*)d_in[2];
  const float* Wq_d   = (const float*)d_in[3];
  const float* Wkv_c  = (const float*)d_in[4];
  const float* kv_nw  = (const float*)d_in[5];
  const float* Wkv_d  = (const float*)d_in[6];
  const float* Wo     = (const float*)d_in[7];

  float* out = (float*)d_out;                       // (1024, 5120)
  float* ckv = out + (size_t)1024 * 5120;           // (1024, 576)  output #2

  char* ws = (char*)d_ws;
  u16*   h_bf  = (u16*)ws;   ws += (size_t)1024 * 5120 * 2;
  float* q_c   = (float*)ws; ws += (size_t)1024 * 1536 * 4;
  u16*   q_n   = (u16*)ws;   ws += (size_t)1024 * 1536 * 2;
  u16*   qbuf  = (u16*)ws;   ws += (size_t)1024 * 24576 * 2;
  u16*   kv_n  = (u16*)ws;   ws += (size_t)1024 * 512 * 2;
  u16*   kvbuf = (u16*)ws;   ws += (size_t)1024 * 32768 * 2;
  u16*   krope = (u16*)ws;   ws += (size_t)1024 * 64 * 2;
  u16*   vt    = (u16*)ws;   ws += (size_t)128 * 128 * 1024 * 2;
  u16*   attno = (u16*)ws;   ws += (size_t)1024 * 16384 * 2;
  // transposed bf16 weights [Npad][K]:
  u16*   wtqc  = (u16*)ws;   ws += (size_t)1536 * 5120 * 2;
  u16*   wtkvc = (u16*)ws;   ws += (size_t)640 * 5120 * 2;
  u16*   wtqd  = (u16*)ws;   ws += (size_t)24576 * 1536 * 2;
  u16*   wtkvd = (u16*)ws;   ws += (size_t)32768 * 512 * 2;
  u16*   wto   = (u16*)ws;   ws += (size_t)5120 * 16384 * 2;

  dim3 b256(256), b512(512), bwt(32, 8);

  // zero atomic-accumulated outputs: d_out (out+ckv) and q_c
  k_zero<<<5696, b256, 0, stream>>>(out, (1024 * 5120 + 1024 * 576) / 4);
  k_zero<<<1536, b256, 0, stream>>>(q_c, 1024 * 1536 / 4);

  // weight cast+transpose
  k_wt<<<dim3(48, 160),  bwt, 0, stream>>>(Wq_c,  wtqc,  5120, 1536);
  k_wt<<<dim3(20, 160),  bwt, 0, stream>>>(Wkv_c, wtkvc, 5120, 576);
  k_wt<<<dim3(768, 48),  bwt, 0, stream>>>(Wq_d,  wtqd,  1536, 24576);
  k_wt<<<dim3(1024, 16), bwt, 0, stream>>>(Wkv_d, wtkvd, 512,  32768);
  k_wt<<<dim3(160, 512), bwt, 0, stream>>>(Wo,    wto,   16384, 5120);

  k_cast<<<5120, b256, 0, stream>>>(hidden, h_bf, 1024 * 5120 / 4);

  // q-down (split-K x4) and kv-down (split-K x8), fp32 atomic accumulate
  k_gemm_bt<2><<<dim3(12, 8, 4), b256, 0, stream>>>(h_bf, wtqc,  q_c, 1024, 1536, 5120, 1280);
  k_gemm_bt<2><<<dim3(5, 8, 8),  b256, 0, stream>>>(h_bf, wtkvc, ckv, 1024, 576,  5120, 640);

  k_rmsnorm<<<1024, b256, 0, stream>>>(q_c, 1536, 1536, q_nw, q_n);
  k_rmsnorm<<<1024, b256, 0, stream>>>(ckv, 576,  512,  kv_nw, kv_n);

  // up-projections: 256^2 8-phase, bf16 out (384 / 512 blocks, both %8==0)
  k_gemm256<1><<<dim3(96, 4, 1),  b512, 0, stream>>>(q_n,  wtqd,  qbuf,  1024, 24576, 1536, 1536);
  k_gemm256<1><<<dim3(128, 4, 1), b512, 0, stream>>>(kv_n, wtkvd, kvbuf, 1024, 32768, 512,  512);

  k_rope_q<<<16384, b256, 0, stream>>>(qbuf);
  k_rope_k<<<128,   b256, 0, stream>>>(ckv, krope);

  k_transpose_v<<<dim3(32, 4, 128), dim3(32, 8), 0, stream>>>(kvbuf, vt);

  k_attn<<<dim3(128, 16), b256, 0, stream>>>(qbuf, kvbuf, krope, vt, attno);

  // out-proj: 256^2 8-phase, split-K x4, fp32 atomic accumulate (320 blocks)
  k_gemm256<2><<<dim3(20, 4, 4), b512, 0, stream>>>(attno, wto, out, 1024, 5120, 16384, 4096);
}

// Round 3
// 1543.090 us; speedup vs baseline: 1.0675x; 1.0675x over previous
//
#include <hip/hip_runtime.h>

// MLA forward, MI355X gfx950. Round 5 (= round 4 resubmitted; round 4 never ran
// due to GPU acquisition timeout).
// H=128 DN=128 DR=64 DV=128 RQ=1536 RKV=512 HSZ=5120 S=1024
//
// Changes vs round 3 (1647 us, out-proj 329 us @ MfmaUtil 21%, 15.7M LDS conflicts):
//  - k_gemm256: FULL 3-bit LDS slot swizzle (slot ^= row&7 at 16B granularity).
//    Round 3 used only (row&4) -> residual 4..8-way ds_read_b128 conflicts
//    (15.7M conflict-cycles/dispatch = ~4 extra cyc/read). Applied as inverse
//    swizzle on the global_load_lds source and forward swizzle on ds_read.
//  - out-proj split-K x3 uneven (86/86/84 K-tiles) -> 240 blocks = ONE
//    dispatch round at 1 block/CU (was 320 -> 2 rounds, 2nd round 25% busy).
//  - k_attn: revert Ks/Vs XOR swizzle (row strides 25/9 slots are odd mod 8 ->
//    naturally conflict-free; the XOR made Ks 4-way). Keep Ps swizzle
//    (stride 8 slots == 0 mod 8 was the real 16-way conflict).

typedef __attribute__((ext_vector_type(8))) short short8;
typedef __attribute__((ext_vector_type(4))) float f32x4;
typedef unsigned short u16;

__device__ __forceinline__ u16 f2bf(float f) {
  union { float f; unsigned u; } v; v.f = f;
  unsigned r = v.u + 0x7fffu + ((v.u >> 16) & 1u);   // RNE
  return (u16)(r >> 16);
}
__device__ __forceinline__ float bf2f(u16 s) {
  union { unsigned u; float f; } v; v.u = ((unsigned)s) << 16; return v.f;
}

__device__ __forceinline__ void gl_lds16(const u16* g, u16* l) {
  __builtin_amdgcn_global_load_lds(
      (const __attribute__((address_space(1))) void*)g,
      (__attribute__((address_space(3))) void*)l,
      16, 0, 0);
}

#define BARX()  asm volatile("s_barrier" ::: "memory")
#define LGKM0() do { asm volatile("s_waitcnt lgkmcnt(0)" ::: "memory"); \
                     __builtin_amdgcn_sched_barrier(0); } while (0)
#define VMW(n)  asm volatile("s_waitcnt vmcnt(" #n ")" ::: "memory")

// ---------------------------------------------------------------- zero fill
__global__ void k_zero(float* __restrict__ p, int n4) {
  int i = blockIdx.x * 256 + threadIdx.x;
  if (i < n4) ((float4*)p)[i] = make_float4(0.f, 0.f, 0.f, 0.f);
}

// ---------------------------------------------------------------- cast
__global__ void k_cast(const float* __restrict__ in, u16* __restrict__ out, int n4) {
  int i = blockIdx.x * 256 + threadIdx.x;
  if (i < n4) {
    float4 v = ((const float4*)in)[i];
    ushort4 o;
    o.x = f2bf(v.x); o.y = f2bf(v.y); o.z = f2bf(v.z); o.w = f2bf(v.w);
    ((ushort4*)out)[i] = o;
  }
}

// ---------------------------------------------------------------- weight cast+transpose
// W fp32 [K][N] -> WT bf16 [Npad][K]; pad rows (n>=N) zeroed.
__global__ void k_wt(const float* __restrict__ W, u16* __restrict__ WT,
                     int K, int N) {
  __shared__ u16 t[32][33];
  int n0 = blockIdx.x * 32, k0 = blockIdx.y * 32;
  int tx = threadIdx.x, ty = threadIdx.y;   // 32 x 8
#pragma unroll
  for (int r = 0; r < 4; r++) {
    int kl = ty + r * 8, n = n0 + tx;
    float v = (n < N) ? W[(size_t)(k0 + kl) * N + n] : 0.f;
    t[kl][tx] = f2bf(v);
  }
  __syncthreads();
#pragma unroll
  for (int r = 0; r < 4; r++) {
    int nl = ty + r * 8;
    WT[(size_t)(n0 + nl) * K + k0 + tx] = t[tx][nl];
  }
}

// ---------------------------------------------------------------- GEMM 128^2 (m97 structure)
// kept for the small split-K down-projections.
template<int OUT_MODE>   // 0 fp32, 1 bf16, 2 fp32 atomicAdd
__global__ __launch_bounds__(256) void k_gemm_bt(
    const u16* __restrict__ A, const u16* __restrict__ BT,
    void* __restrict__ Cv, int M, int N, int K, int kChunk)
{
  __shared__ u16 As[128 * 32];
  __shared__ u16 Bs[128 * 32];
  const int tid = threadIdx.x;
  const int wave = tid >> 6, lane = tid & 63;
  const int qd = lane >> 4, l = lane & 15;
  const int bn0 = blockIdx.x * 128, bm0 = blockIdx.y * 128;
  const int k0 = blockIdx.z * kChunk;
  const int wrow = (wave >> 1) * 64, wcol = (wave & 1) * 64;
  const f32x4 fzero = {0.f, 0.f, 0.f, 0.f};

  f32x4 acc[4][4];
#pragma unroll
  for (int i = 0; i < 4; i++)
#pragma unroll
    for (int j = 0; j < 4; j++) acc[i][j] = fzero;

  const int sm = wave * 16 + (lane >> 2);
  const int sc = (lane & 3) * 8;
  const u16* a0 = A  + (size_t)(bm0 + sm) * K + sc;
  const u16* a1 = A  + (size_t)(bm0 + 64 + sm) * K + sc;
  const u16* b0 = BT + (size_t)(bn0 + sm) * K + sc;
  const u16* b1 = BT + (size_t)(bn0 + 64 + sm) * K + sc;
  u16* aD0 = As + wave * 512;
  u16* aD1 = As + 2048 + wave * 512;
  u16* bD0 = Bs + wave * 512;
  u16* bD1 = Bs + 2048 + wave * 512;

  const int kEnd = k0 + kChunk;
  for (int kt = k0; kt < kEnd; kt += 32) {
    gl_lds16(a0 + kt, aD0);
    gl_lds16(a1 + kt, aD1);
    gl_lds16(b0 + kt, bD0);
    gl_lds16(b1 + kt, bD1);
    __syncthreads();

    short8 af[4], bfr[4];
#pragma unroll
    for (int i = 0; i < 4; i++) af[i]  = *(const short8*)&As[(wrow + i * 16 + l) * 32 + qd * 8];
#pragma unroll
    for (int j = 0; j < 4; j++) bfr[j] = *(const short8*)&Bs[(wcol + j * 16 + l) * 32 + qd * 8];
#pragma unroll
    for (int i = 0; i < 4; i++)
#pragma unroll
      for (int j = 0; j < 4; j++)
        acc[i][j] = __builtin_amdgcn_mfma_f32_16x16x32_bf16(af[i], bfr[j], acc[i][j], 0, 0, 0);
    __syncthreads();
  }

#pragma unroll
  for (int i = 0; i < 4; i++) {
    int r = bm0 + wrow + i * 16 + qd * 4;
#pragma unroll
    for (int j = 0; j < 4; j++) {
      int c = bn0 + wcol + j * 16 + l;
      if (c < N) {
#pragma unroll
        for (int reg = 0; reg < 4; ++reg) {
          if (OUT_MODE == 1)
            ((u16*)Cv)[(size_t)(r + reg) * N + c] = f2bf(acc[i][j][reg]);
          else if (OUT_MODE == 0)
            ((float*)Cv)[(size_t)(r + reg) * N + c] = acc[i][j][reg];
          else
            atomicAdd(&((float*)Cv)[(size_t)(r + reg) * N + c], acc[i][j][reg]);
        }
      }
    }
  }
}

// ---------------------------------------------------------------- GEMM 256^2, 8-phase
// C[M,N] = A[M,K] @ BT[N,K], bf16 in. 512 threads = 8 waves (2M x 4N); per-wave
// C 128x64 (8x4 fragments of 16x16x32). BK=64, two K-tiles per iteration.
// LDS: 2 dbuf x (256x64) x {A,B} x bf16 = 128 KiB.
// Swizzle: rows are 64 u16 = 128 B = one bank period = 8 x 16B slots.
// Physical slot = logical slot ^ (row & 7) (3-bit involution). Staging keeps
// the LDS dest linear (global_load_lds constraint) and inverse-swizzles the
// global source column; ds_reads apply the forward swizzle. A wave's b128 read
// (16 rows x 4 qd-slots) then covers all 8 slots per 8-lane group -> <=2-way.
// Pipeline: vmcnt(6) only at ph4/ph8 (counted, never 0 in the main loop).
template<int OUT_MODE>   // 1 bf16 store, 2 fp32 atomicAdd (split-K)
__global__ __launch_bounds__(512, 2) void k_gemm256(
    const u16* __restrict__ A, const u16* __restrict__ BT, void* __restrict__ Cv,
    int M, int N, int K, int kChunk)
{
  __shared__ u16 As[2][16384];   // per buf: 256 rows x 64 cols bf16 (32 KB)
  __shared__ u16 Bs[2][16384];
  const int tid = threadIdx.x;
  const int w = tid >> 6, lane = tid & 63;
  const int wm = w >> 2, wn = w & 3;
  const int qd = lane >> 4, l = lane & 15;

  // T1: XCD-aware swizzle. All launch grids have nwg % 8 == 0.
  const int gx = gridDim.x, gy = gridDim.y;
  const int nwg = gx * gy * gridDim.z;
  int lin = blockIdx.x + gx * (blockIdx.y + gy * blockIdx.z);
  int lin2 = (lin & 7) * (nwg >> 3) + (lin >> 3);
  const int bx = lin2 % gx;
  const int byz = lin2 / gx;
  const int bm0 = (byz % gy) * 256;
  const int bn0 = bx * 256;
  const int k0  = (byz / gy) * kChunk;
  const int kcap = K - k0;
  const int myChunk = (kcap < kChunk) ? kcap : kChunk;  // last z-chunk may be shorter
  const int ntiles = myChunk >> 6;       // even, >= 2
  const int niter  = ntiles >> 1;

  f32x4 acc[8][4];
  const f32x4 fz = {0.f, 0.f, 0.f, 0.f};
#pragma unroll
  for (int i = 0; i < 8; i++)
#pragma unroll
    for (int j = 0; j < 4; j++) acc[i][j] = fz;

// stage one 128-row half-tile (hf) of K-tile tI of matP (rows rb..rb+255,
// row stride K) into dstB. Linear LDS dest (wave-uniform base); source column
// inverse-swizzled: physical slot p holds logical slot p ^ (row&7).
#define STG(matP, rb, tI, hf, dstB)                                           \
  {                                                                           \
    const int _kt = k0 + (tI) * 64;                                           \
    _Pragma("unroll")                                                         \
    for (int _L = 0; _L < 2; ++_L) {                                          \
      const int _ob = (hf) * 8192 + _L * 4096 + w * 512;   /* u16, uniform */ \
      const int _o  = _ob + lane * 8;                                         \
      const int _r  = _o >> 6;                                                \
      const int _c  = (_o & 63) ^ ((_r & 7) << 3);                            \
      gl_lds16((matP) + (size_t)((rb) + _r) * K + _kt + _c, (dstB) + _ob);    \
    }                                                                         \
  }

#define LDA4(buf, mh)                                                         \
  _Pragma("unroll")                                                           \
  for (int _i = 0; _i < 4; ++_i) {                                            \
    const int _row = wm * 128 + (mh) * 64 + _i * 16 + l;                      \
    const int _sw = (_row & 7) << 3;                                          \
    af[_i][0] = *(const short8*)&(buf)[_row * 64 + ((qd * 8) ^ _sw)];         \
    af[_i][1] = *(const short8*)&(buf)[_row * 64 + ((32 + qd * 8) ^ _sw)];    \
  }

#define LDB2(buf, nh, dst)                                                    \
  _Pragma("unroll")                                                           \
  for (int _j = 0; _j < 2; ++_j) {                                            \
    const int _row = wn * 64 + (nh) * 32 + _j * 16 + l;                       \
    const int _sw = (_row & 7) << 3;                                          \
    dst[_j][0] = *(const short8*)&(buf)[_row * 64 + ((qd * 8) ^ _sw)];        \
    dst[_j][1] = *(const short8*)&(buf)[_row * 64 + ((32 + qd * 8) ^ _sw)];   \
  }

#define MFQ(mh, nh, bsrc)                                                     \
  __builtin_amdgcn_s_setprio(1);                                              \
  _Pragma("unroll")                                                           \
  for (int _i = 0; _i < 4; ++_i)                                              \
    _Pragma("unroll")                                                         \
    for (int _j = 0; _j < 2; ++_j) {                                          \
      f32x4 _a = acc[(mh) * 4 + _i][(nh) * 2 + _j];                           \
      _a = __builtin_amdgcn_mfma_f32_16x16x32_bf16(af[_i][0], bsrc[_j][0], _a, 0, 0, 0); \
      _a = __builtin_amdgcn_mfma_f32_16x16x32_bf16(af[_i][1], bsrc[_j][1], _a, 0, 0, 0); \
      acc[(mh) * 4 + _i][(nh) * 2 + _j] = _a;                                 \
    }                                                                         \
  __builtin_amdgcn_s_setprio(0);

  // prologue: tile0 fully + tile1 {B0,B1,A0}; tile1.A1 goes at ph1 of j=0.
  STG(BT, bn0, 0, 0, Bs[0]); STG(BT, bn0, 0, 1, Bs[0]);
  STG(A,  bm0, 0, 0, As[0]); STG(A,  bm0, 0, 1, As[0]);
  STG(BT, bn0, 1, 0, Bs[1]); STG(BT, bn0, 1, 1, Bs[1]);
  STG(A,  bm0, 1, 0, As[1]);
  VMW(6);            // tile0's 8 loads (oldest) retired
  BARX();

  short8 af[4][2], bf0[2][2], bf1[2][2];
  for (int j = 0; j < niter; ++j) {
    int t2 = 2 * j + 2; if (t2 >= ntiles) t2 -= ntiles;   // wrap: redundant stage, safe
    int t3 = t2 + 1;

    // ---- tile 2j (buf0) ----
    LDA4(As[0], 0); LDB2(Bs[0], 0, bf0);                 // ph1
    STG(A, bm0, 2 * j + 1, 1, As[1]);
    BARX(); LGKM0();
    MFQ(0, 0, bf0);
    BARX();

    LDB2(Bs[0], 1, bf1);                                 // ph2
    BARX(); LGKM0();
    MFQ(0, 1, bf1);
    BARX();

    LDA4(As[0], 1);                                      // ph3
    STG(BT, bn0, t2, 0, Bs[0]); STG(BT, bn0, t2, 1, Bs[0]);
    BARX(); LGKM0();
    MFQ(1, 1, bf1);
    BARX();

    STG(A, bm0, t2, 0, As[0]);                           // ph4
    VMW(6);                                              // tile 2j+1 fully retired
    BARX(); LGKM0();
    MFQ(1, 0, bf0);
    BARX();

    // ---- tile 2j+1 (buf1) ----
    LDA4(As[1], 0); LDB2(Bs[1], 0, bf0);                 // ph5
    STG(A, bm0, t2, 1, As[0]);
    BARX(); LGKM0();
    MFQ(0, 0, bf0);
    BARX();

    LDB2(Bs[1], 1, bf1);                                 // ph6
    BARX(); LGKM0();
    MFQ(0, 1, bf1);
    BARX();

    LDA4(As[1], 1);                                      // ph7
    STG(BT, bn0, t3, 0, Bs[1]); STG(BT, bn0, t3, 1, Bs[1]);
    BARX(); LGKM0();
    MFQ(1, 1, bf1);
    BARX();

    STG(A, bm0, t3, 0, As[1]);                           // ph8
    VMW(6);                                              // tile 2j+2 fully retired
    BARX(); LGKM0();
    MFQ(1, 0, bf0);
    BARX();
  }
  asm volatile("s_waitcnt vmcnt(0)" ::: "memory");

#undef STG
#undef LDA4
#undef LDB2
#undef MFQ

  // epilogue: C/D layout col=lane&15, row=(lane>>4)*4+reg
#pragma unroll
  for (int i = 0; i < 8; ++i) {
    int r = bm0 + wm * 128 + i * 16 + qd * 4;
#pragma unroll
    for (int jj = 0; jj < 4; ++jj) {
      int c = bn0 + wn * 64 + jj * 16 + l;
#pragma unroll
      for (int reg = 0; reg < 4; ++reg) {
        if (OUT_MODE == 1)
          ((u16*)Cv)[(size_t)(r + reg) * N + c] = f2bf(acc[i][jj][reg]);
        else
          atomicAdd(&((float*)Cv)[(size_t)(r + reg) * N + c], acc[i][jj][reg]);
      }
    }
  }
}

// ---------------------------------------------------------------- rmsnorm
__global__ void k_rmsnorm(const float* __restrict__ in, int istride, int W,
                          const float* __restrict__ w, u16* __restrict__ out) {
  int row = blockIdx.x, tid = threadIdx.x;
  const float* x = in + (size_t)row * istride;
  float s = 0.f;
  for (int i = tid; i < W; i += 256) { float v = x[i]; s += v * v; }
#pragma unroll
  for (int o = 32; o; o >>= 1) s += __shfl_xor(s, o);
  __shared__ float red[4];
  if ((tid & 63) == 0) red[tid >> 6] = s;
  __syncthreads();
  float tot = red[0] + red[1] + red[2] + red[3];
  float sc = rsqrtf(tot / (float)W + 1e-6f);
  for (int i = tid; i < W; i += 256)
    out[(size_t)row * W + i] = f2bf(x[i] * sc * w[i]);
}

// ---------------------------------------------------------------- rope
__global__ void k_rope_q(u16* __restrict__ q) {   // in-place on (1024, 128*192)
  int idx = blockIdx.x * 256 + threadIdx.x;       // 1024*128*32
  int s = idx >> 12, r = idx & 4095, h = r >> 5, i = r & 31;
  float inv = expf((float)i * (-logf(10000.f) / 32.f));
  float ang = (float)s * inv, sn, cs;
  sincosf(ang, &sn, &cs);
  u16* p1 = q + (size_t)s * 24576 + h * 192 + 128 + i;
  u16* p2 = p1 + 32;
  float x1 = bf2f(*p1), x2 = bf2f(*p2);
  *p1 = f2bf(x1 * cs - x2 * sn);
  *p2 = f2bf(x2 * cs + x1 * sn);
}

__global__ void k_rope_k(const float* __restrict__ ckv, u16* __restrict__ kr) {
  int idx = blockIdx.x * 256 + threadIdx.x;       // 1024*32
  int s = idx >> 5, i = idx & 31;
  float inv = expf((float)i * (-logf(10000.f) / 32.f));
  float ang = (float)s * inv, sn, cs;
  sincosf(ang, &sn, &cs);
  const float* src = ckv + (size_t)s * 576 + 512;
  float x1 = src[i], x2 = src[i + 32];
  kr[s * 64 + i]      = f2bf(x1 * cs - x2 * sn);
  kr[s * 64 + 32 + i] = f2bf(x2 * cs + x1 * sn);
}

// ---------------------------------------------------------------- V transpose
__global__ void k_transpose_v(const u16* __restrict__ kv, u16* __restrict__ vt) {
  __shared__ u16 tile[32][33];
  int h = blockIdx.z, s0 = blockIdx.x * 32, d0 = blockIdx.y * 32;
  int tx = threadIdx.x, ty = threadIdx.y;   // 32 x 8
#pragma unroll
  for (int k2 = 0; k2 < 4; k2++) {
    int r = ty + k2 * 8;
    tile[r][tx] = kv[(size_t)(s0 + r) * 32768 + h * 256 + 128 + d0 + tx];
  }
  __syncthreads();
#pragma unroll
  for (int k2 = 0; k2 < 4; k2++) {
    int r = ty + k2 * 8;
    vt[(size_t)h * 131072 + (size_t)(d0 + r) * 1024 + s0 + tx] = tile[tx][r];
  }
}

// ---------------------------------------------------------------- attention
// One block = (head h, 64 q-rows). 4 waves x 16 q-rows. 16 kv-tiles of 64.
// Ks (stride 200 u16 = 25 slots, odd mod 8) and Vs (72 u16 = 9 slots) are
// NATURALLY bank-staggered -> direct indexing, no swizzle. Ps (stride 64 u16 =
// 8 slots == 0 mod 8) keeps the 3-bit XOR swizzle (was the 16-way conflict).
__global__ __launch_bounds__(256, 2) void k_attn(
    const u16* __restrict__ q,    // (1024, 128*192)
    const u16* __restrict__ kvn,  // (1024, 128*256): k_nope at h*256+0..127
    const u16* __restrict__ kr,   // (1024, 64) roped k_rope, shared across heads
    const u16* __restrict__ vt,   // (128, 128, 1024) V^T per head
    u16* __restrict__ o)          // (1024, 128*128)
{
  __shared__ u16 Ks[64][200];
  __shared__ u16 Vs[128][72];
  __shared__ u16 Ps[4][16][64];
  const int h = blockIdx.x, q0 = blockIdx.y * 64;
  const int tid = threadIdx.x, wave = tid >> 6, lane = tid & 63;
  const int qd = lane >> 4, l = lane & 15;
  const float scale = 0.07216878364870323f;   // 1/sqrt(192)
  const f32x4 fzero = {0.f, 0.f, 0.f, 0.f};

  short8 qf[6];
  {
    const u16* qp = q + (size_t)(q0 + wave * 16 + l) * 24576 + h * 192 + qd * 8;
#pragma unroll
    for (int kk = 0; kk < 6; kk++) qf[kk] = *(const short8*)(qp + kk * 32);
  }

  f32x4 Of[8];
#pragma unroll
  for (int jt = 0; jt < 8; jt++) Of[jt] = fzero;
  float m_i[4] = {-1e30f, -1e30f, -1e30f, -1e30f};
  float l_i[4] = {0.f, 0.f, 0.f, 0.f};

  for (int kt = 0; kt < 16; ++kt) {
    const int kv0 = kt * 64;
    __syncthreads();
#pragma unroll
    for (int it = 0; it < 6; ++it) {
      int ci = it * 256 + tid;
      int r = ci / 24, c = ci % 24;
      int col0 = c * 8;
      const u16* src = (col0 < 128)
          ? kvn + (size_t)(kv0 + r) * 32768 + h * 256 + col0
          : kr + (size_t)(kv0 + r) * 64 + (col0 - 128);
      *(short8*)&Ks[r][col0] = *(const short8*)src;
    }
#pragma unroll
    for (int it = 0; it < 4; ++it) {
      int ci = it * 256 + tid;
      int dv = ci >> 3, c = ci & 7;
      *(short8*)&Vs[dv][c * 8] =
          *(const short8*)(vt + (size_t)h * 131072 + (size_t)dv * 1024 + kv0 + c * 8);
    }
    __syncthreads();

    f32x4 sf[4];
#pragma unroll
    for (int j = 0; j < 4; j++) sf[j] = fzero;
#pragma unroll
    for (int kk = 0; kk < 6; kk++)
#pragma unroll
      for (int j = 0; j < 4; j++) {
        short8 bf = *(const short8*)&Ks[j * 16 + l][kk * 32 + qd * 8];
        sf[j] = __builtin_amdgcn_mfma_f32_16x16x32_bf16(qf[kk], bf, sf[j], 0, 0, 0);
      }
#pragma unroll
    for (int j = 0; j < 4; j++) sf[j] *= scale;

#pragma unroll
    for (int reg = 0; reg < 4; ++reg) {
      float mx = fmaxf(fmaxf(sf[0][reg], sf[1][reg]), fmaxf(sf[2][reg], sf[3][reg]));
#pragma unroll
      for (int off = 1; off < 16; off <<= 1) mx = fmaxf(mx, __shfl_xor(mx, off));
      float mnew = fmaxf(m_i[reg], mx);
      float alpha = expf(m_i[reg] - mnew);
      m_i[reg] = mnew;
      float rs = 0.f;
      int prow = qd * 4 + reg;
#pragma unroll
      for (int j = 0; j < 4; j++) {
        float p = expf(sf[j][reg] - mnew);
        rs += p;
        int g = (j * 2 + (l >> 3)) ^ (prow & 7);
        Ps[wave][prow][g * 8 + (l & 7)] = f2bf(p);
      }
#pragma unroll
      for (int off = 1; off < 16; off <<= 1) rs += __shfl_xor(rs, off);
      l_i[reg] = l_i[reg] * alpha + rs;
#pragma unroll
      for (int jt = 0; jt < 8; jt++) Of[jt][reg] *= alpha;
    }

#pragma unroll
    for (int ks = 0; ks < 2; ++ks) {
      short8 pf = *(const short8*)&Ps[wave][l][(((ks * 4 + qd) ^ (l & 7))) * 8];
#pragma unroll
      for (int jt = 0; jt < 8; jt++) {
        short8 vf = *(const short8*)&Vs[jt * 16 + l][ks * 32 + qd * 8];
        Of[jt] = __builtin_amdgcn_mfma_f32_16x16x32_bf16(pf, vf, Of[jt], 0, 0, 0);
      }
    }
  }

#pragma unroll
  for (int reg = 0; reg < 4; ++reg) {
    float inv_l = 1.f / l_i[reg];
    int row = q0 + wave * 16 + qd * 4 + reg;
#pragma unroll
    for (int jt = 0; jt < 8; jt++)
      o[(size_t)row * 16384 + h * 128 + jt * 16 + l] = f2bf(Of[jt][reg] * inv_l);
  }
}

// ---------------------------------------------------------------- launch
extern "C" void kernel_launch(void* const* d_in, const int* in_sizes, int n_in,
                              void* d_out, int out_size, void* d_ws, size_t ws_size,
                              hipStream_t stream)
{
  const float* hidden = (const float*)d_in[0];
  const float* Wq_c   = (const float*)d_in[1];
  const float* q_nw   = (const float*)d_in[2];
  const float* Wq_d   = (const float*)d_in[3];
  const float* Wkv_c  = (const float*)d_in[4];
  const float* kv_nw  = (const float*)d_in[5];
  const float* Wkv_d  = (const float*)d_in[6];
  const float* Wo     = (const float*)d_in[7];

  float* out = (float*)d_out;                       // (1024, 5120)
  float* ckv = out + (size_t)1024 * 5120;           // (1024, 576)  output #2

  char* ws = (char*)d_ws;
  u16*   h_bf  = (u16*)ws;   ws += (size_t)1024 * 5120 * 2;
  float* q_c   = (float*)ws; ws += (size_t)1024 * 1536 * 4;
  u16*   q_n   = (u16*)ws;   ws += (size_t)1024 * 1536 * 2;
  u16*   qbuf  = (u16*)ws;   ws += (size_t)1024 * 24576 * 2;
  u16*   kv_n  = (u16*)ws;   ws += (size_t)1024 * 512 * 2;
  u16*   kvbuf = (u16*)ws;   ws += (size_t)1024 * 32768 * 2;
  u16*   krope = (u16*)ws;   ws += (size_t)1024 * 64 * 2;
  u16*   vt    = (u16*)ws;   ws += (size_t)128 * 128 * 1024 * 2;
  u16*   attno = (u16*)ws;   ws += (size_t)1024 * 16384 * 2;
  // transposed bf16 weights [Npad][K]:
  u16*   wtqc  = (u16*)ws;   ws += (size_t)1536 * 5120 * 2;
  u16*   wtkvc = (u16*)ws;   ws += (size_t)640 * 5120 * 2;
  u16*   wtqd  = (u16*)ws;   ws += (size_t)24576 * 1536 * 2;
  u16*   wtkvd = (u16*)ws;   ws += (size_t)32768 * 512 * 2;
  u16*   wto   = (u16*)ws;   ws += (size_t)5120 * 16384 * 2;

  dim3 b256(256), b512(512), bwt(32, 8);

  // zero atomic-accumulated outputs: d_out (out+ckv) and q_c
  k_zero<<<5696, b256, 0, stream>>>(out, (1024 * 5120 + 1024 * 576) / 4);
  k_zero<<<1536, b256, 0, stream>>>(q_c, 1024 * 1536 / 4);

  // weight cast+transpose
  k_wt<<<dim3(48, 160),  bwt, 0, stream>>>(Wq_c,  wtqc,  5120, 1536);
  k_wt<<<dim3(20, 160),  bwt, 0, stream>>>(Wkv_c, wtkvc, 5120, 576);
  k_wt<<<dim3(768, 48),  bwt, 0, stream>>>(Wq_d,  wtqd,  1536, 24576);
  k_wt<<<dim3(1024, 16), bwt, 0, stream>>>(Wkv_d, wtkvd, 512,  32768);
  k_wt<<<dim3(160, 512), bwt, 0, stream>>>(Wo,    wto,   16384, 5120);

  k_cast<<<5120, b256, 0, stream>>>(hidden, h_bf, 1024 * 5120 / 4);

  // q-down (split-K x4) and kv-down (split-K x8), fp32 atomic accumulate
  k_gemm_bt<2><<<dim3(12, 8, 4), b256, 0, stream>>>(h_bf, wtqc,  q_c, 1024, 1536, 5120, 1280);
  k_gemm_bt<2><<<dim3(5, 8, 8),  b256, 0, stream>>>(h_bf, wtkvc, ckv, 1024, 576,  5120, 640);

  k_rmsnorm<<<1024, b256, 0, stream>>>(q_c, 1536, 1536, q_nw, q_n);
  k_rmsnorm<<<1024, b256, 0, stream>>>(ckv, 576,  512,  kv_nw, kv_n);

  // up-projections: 256^2 8-phase, bf16 out (384 / 512 blocks, both %8==0)
  k_gemm256<1><<<dim3(96, 4, 1),  b512, 0, stream>>>(q_n,  wtqd,  qbuf,  1024, 24576, 1536, 1536);
  k_gemm256<1><<<dim3(128, 4, 1), b512, 0, stream>>>(kv_n, wtkvd, kvbuf, 1024, 32768, 512,  512);

  k_rope_q<<<16384, b256, 0, stream>>>(qbuf);
  k_rope_k<<<128,   b256, 0, stream>>>(ckv, krope);

  k_transpose_v<<<dim3(32, 4, 128), dim3(32, 8), 0, stream>>>(kvbuf, vt);

  k_attn<<<dim3(128, 16), b256, 0, stream>>>(qbuf, kvbuf, krope, vt, attno);

  // out-proj: 256^2 8-phase, split-K x3 uneven (86/86/84 K-tiles) -> 240
  // blocks = one full dispatch round at 1 block/CU. fp32 atomic accumulate.
  k_gemm256<2><<<dim3(20, 4, 3), b512, 0, stream>>>(attno, wto, out, 1024, 5120, 16384, 5504);
}

// Round 5
// 1525.175 us; speedup vs baseline: 1.0800x; 1.0117x over previous
//
#include <hip/hip_runtime.h>

// MLA forward, MI355X gfx950. Round 7 (= round 6 resubmitted; round 6 never ran
// due to GPU acquisition timeout).
// H=128 DN=128 DR=64 DV=128 RQ=1536 RKV=512 HSZ=5120 S=1024
//
// Changes vs round 5 (1543 us; k_attn 310 us = top dispatch, MfmaUtil 11.7%,
// 2.1e7 LDS bank conflicts from the Ps scalar-u16 path, occupancy 21.8%):
//  - k_attn rewritten with swapped MFMA operands (T12 mechanism):
//      QK: sf = mfma(K_frag, Q_frag)  -> S^T, lane owns q-row (q = lane&15)
//      softmax: in-lane 16-value tree + 2 shfl_xor (was 32 shfls), scalar m/l
//      P^T fragment built in-register: 8 RNE packs + 16 ds_bpermute + 8 selects
//      (replaces 16 conflicted scalar u16 LDS writes + 2 conflicted b128 reads)
//      PV: Of = mfma(V_frag, P_frag) -> O^T; epilogue LDS transpose (reuses Ks)
//    Ps LDS buffer deleted -> 44 KB/block -> __launch_bounds__(256,3) = 3 blk/CU.
//    s_setprio(1) around both MFMA clusters (T5).
//  - everything else unchanged from round 5.

typedef __attribute__((ext_vector_type(8))) short short8;
typedef __attribute__((ext_vector_type(4))) float f32x4;
typedef unsigned short u16;

__device__ __forceinline__ u16 f2bf(float f) {
  union { float f; unsigned u; } v; v.f = f;
  unsigned r = v.u + 0x7fffu + ((v.u >> 16) & 1u);   // RNE
  return (u16)(r >> 16);
}
__device__ __forceinline__ float bf2f(u16 s) {
  union { unsigned u; float f; } v; v.u = ((unsigned)s) << 16; return v.f;
}
__device__ __forceinline__ unsigned pk2(float a, float b) {   // RNE bf16 pair
  return (unsigned)f2bf(a) | ((unsigned)f2bf(b) << 16);
}

__device__ __forceinline__ void gl_lds16(const u16* g, u16* l) {
  __builtin_amdgcn_global_load_lds(
      (const __attribute__((address_space(1))) void*)g,
      (__attribute__((address_space(3))) void*)l,
      16, 0, 0);
}

#define BARX()  asm volatile("s_barrier" ::: "memory")
#define LGKM0() do { asm volatile("s_waitcnt lgkmcnt(0)" ::: "memory"); \
                     __builtin_amdgcn_sched_barrier(0); } while (0)
#define VMW(n)  asm volatile("s_waitcnt vmcnt(" #n ")" ::: "memory")

// ---------------------------------------------------------------- zero fill
__global__ void k_zero(float* __restrict__ p, int n4) {
  int i = blockIdx.x * 256 + threadIdx.x;
  if (i < n4) ((float4*)p)[i] = make_float4(0.f, 0.f, 0.f, 0.f);
}

// ---------------------------------------------------------------- cast
__global__ void k_cast(const float* __restrict__ in, u16* __restrict__ out, int n4) {
  int i = blockIdx.x * 256 + threadIdx.x;
  if (i < n4) {
    float4 v = ((const float4*)in)[i];
    ushort4 o;
    o.x = f2bf(v.x); o.y = f2bf(v.y); o.z = f2bf(v.z); o.w = f2bf(v.w);
    ((ushort4*)out)[i] = o;
  }
}

// ---------------------------------------------------------------- weight cast+transpose
// W fp32 [K][N] -> WT bf16 [Npad][K]; pad rows (n>=N) zeroed.
__global__ void k_wt(const float* __restrict__ W, u16* __restrict__ WT,
                     int K, int N) {
  __shared__ u16 t[32][33];
  int n0 = blockIdx.x * 32, k0 = blockIdx.y * 32;
  int tx = threadIdx.x, ty = threadIdx.y;   // 32 x 8
#pragma unroll
  for (int r = 0; r < 4; r++) {
    int kl = ty + r * 8, n = n0 + tx;
    float v = (n < N) ? W[(size_t)(k0 + kl) * N + n] : 0.f;
    t[kl][tx] = f2bf(v);
  }
  __syncthreads();
#pragma unroll
  for (int r = 0; r < 4; r++) {
    int nl = ty + r * 8;
    WT[(size_t)(n0 + nl) * K + k0 + tx] = t[tx][nl];
  }
}

// ---------------------------------------------------------------- GEMM 128^2 (m97 structure)
template<int OUT_MODE>   // 0 fp32, 1 bf16, 2 fp32 atomicAdd
__global__ __launch_bounds__(256) void k_gemm_bt(
    const u16* __restrict__ A, const u16* __restrict__ BT,
    void* __restrict__ Cv, int M, int N, int K, int kChunk)
{
  __shared__ u16 As[128 * 32];
  __shared__ u16 Bs[128 * 32];
  const int tid = threadIdx.x;
  const int wave = tid >> 6, lane = tid & 63;
  const int qd = lane >> 4, l = lane & 15;
  const int bn0 = blockIdx.x * 128, bm0 = blockIdx.y * 128;
  const int k0 = blockIdx.z * kChunk;
  const int wrow = (wave >> 1) * 64, wcol = (wave & 1) * 64;
  const f32x4 fzero = {0.f, 0.f, 0.f, 0.f};

  f32x4 acc[4][4];
#pragma unroll
  for (int i = 0; i < 4; i++)
#pragma unroll
    for (int j = 0; j < 4; j++) acc[i][j] = fzero;

  const int sm = wave * 16 + (lane >> 2);
  const int sc = (lane & 3) * 8;
  const u16* a0 = A  + (size_t)(bm0 + sm) * K + sc;
  const u16* a1 = A  + (size_t)(bm0 + 64 + sm) * K + sc;
  const u16* b0 = BT + (size_t)(bn0 + sm) * K + sc;
  const u16* b1 = BT + (size_t)(bn0 + 64 + sm) * K + sc;
  u16* aD0 = As + wave * 512;
  u16* aD1 = As + 2048 + wave * 512;
  u16* bD0 = Bs + wave * 512;
  u16* bD1 = Bs + 2048 + wave * 512;

  const int kEnd = k0 + kChunk;
  for (int kt = k0; kt < kEnd; kt += 32) {
    gl_lds16(a0 + kt, aD0);
    gl_lds16(a1 + kt, aD1);
    gl_lds16(b0 + kt, bD0);
    gl_lds16(b1 + kt, bD1);
    __syncthreads();

    short8 af[4], bfr[4];
#pragma unroll
    for (int i = 0; i < 4; i++) af[i]  = *(const short8*)&As[(wrow + i * 16 + l) * 32 + qd * 8];
#pragma unroll
    for (int j = 0; j < 4; j++) bfr[j] = *(const short8*)&Bs[(wcol + j * 16 + l) * 32 + qd * 8];
#pragma unroll
    for (int i = 0; i < 4; i++)
#pragma unroll
      for (int j = 0; j < 4; j++)
        acc[i][j] = __builtin_amdgcn_mfma_f32_16x16x32_bf16(af[i], bfr[j], acc[i][j], 0, 0, 0);
    __syncthreads();
  }

#pragma unroll
  for (int i = 0; i < 4; i++) {
    int r = bm0 + wrow + i * 16 + qd * 4;
#pragma unroll
    for (int j = 0; j < 4; j++) {
      int c = bn0 + wcol + j * 16 + l;
      if (c < N) {
#pragma unroll
        for (int reg = 0; reg < 4; ++reg) {
          if (OUT_MODE == 1)
            ((u16*)Cv)[(size_t)(r + reg) * N + c] = f2bf(acc[i][j][reg]);
          else if (OUT_MODE == 0)
            ((float*)Cv)[(size_t)(r + reg) * N + c] = acc[i][j][reg];
          else
            atomicAdd(&((float*)Cv)[(size_t)(r + reg) * N + c], acc[i][j][reg]);
        }
      }
    }
  }
}

// ---------------------------------------------------------------- GEMM 256^2, 8-phase
// (unchanged from round 5 — see comments there)
template<int OUT_MODE>   // 1 bf16 store, 2 fp32 atomicAdd (split-K)
__global__ __launch_bounds__(512, 2) void k_gemm256(
    const u16* __restrict__ A, const u16* __restrict__ BT, void* __restrict__ Cv,
    int M, int N, int K, int kChunk)
{
  __shared__ u16 As[2][16384];
  __shared__ u16 Bs[2][16384];
  const int tid = threadIdx.x;
  const int w = tid >> 6, lane = tid & 63;
  const int wm = w >> 2, wn = w & 3;
  const int qd = lane >> 4, l = lane & 15;

  const int gx = gridDim.x, gy = gridDim.y;
  const int nwg = gx * gy * gridDim.z;
  int lin = blockIdx.x + gx * (blockIdx.y + gy * blockIdx.z);
  int lin2 = (lin & 7) * (nwg >> 3) + (lin >> 3);
  const int bx = lin2 % gx;
  const int byz = lin2 / gx;
  const int bm0 = (byz % gy) * 256;
  const int bn0 = bx * 256;
  const int k0  = (byz / gy) * kChunk;
  const int kcap = K - k0;
  const int myChunk = (kcap < kChunk) ? kcap : kChunk;
  const int ntiles = myChunk >> 6;
  const int niter  = ntiles >> 1;

  f32x4 acc[8][4];
  const f32x4 fz = {0.f, 0.f, 0.f, 0.f};
#pragma unroll
  for (int i = 0; i < 8; i++)
#pragma unroll
    for (int j = 0; j < 4; j++) acc[i][j] = fz;

#define STG(matP, rb, tI, hf, dstB)                                           \
  {                                                                           \
    const int _kt = k0 + (tI) * 64;                                           \
    _Pragma("unroll")                                                         \
    for (int _L = 0; _L < 2; ++_L) {                                          \
      const int _ob = (hf) * 8192 + _L * 4096 + w * 512;   /* u16, uniform */ \
      const int _o  = _ob + lane * 8;                                         \
      const int _r  = _o >> 6;                                                \
      const int _c  = (_o & 63) ^ ((_r & 7) << 3);                            \
      gl_lds16((matP) + (size_t)((rb) + _r) * K + _kt + _c, (dstB) + _ob);    \
    }                                                                         \
  }

#define LDA4(buf, mh)                                                         \
  _Pragma("unroll")                                                           \
  for (int _i = 0; _i < 4; ++_i) {                                            \
    const int _row = wm * 128 + (mh) * 64 + _i * 16 + l;                      \
    const int _sw = (_row & 7) << 3;                                          \
    af[_i][0] = *(const short8*)&(buf)[_row * 64 + ((qd * 8) ^ _sw)];         \
    af[_i][1] = *(const short8*)&(buf)[_row * 64 + ((32 + qd * 8) ^ _sw)];    \
  }

#define LDB2(buf, nh, dst)                                                    \
  _Pragma("unroll")                                                           \
  for (int _j = 0; _j < 2; ++_j) {                                            \
    const int _row = wn * 64 + (nh) * 32 + _j * 16 + l;                       \
    const int _sw = (_row & 7) << 3;                                          \
    dst[_j][0] = *(const short8*)&(buf)[_row * 64 + ((qd * 8) ^ _sw)];        \
    dst[_j][1] = *(const short8*)&(buf)[_row * 64 + ((32 + qd * 8) ^ _sw)];   \
  }

#define MFQ(mh, nh, bsrc)                                                     \
  __builtin_amdgcn_s_setprio(1);                                              \
  _Pragma("unroll")                                                           \
  for (int _i = 0; _i < 4; ++_i)                                              \
    _Pragma("unroll")                                                         \
    for (int _j = 0; _j < 2; ++_j) {                                          \
      f32x4 _a = acc[(mh) * 4 + _i][(nh) * 2 + _j];                           \
      _a = __builtin_amdgcn_mfma_f32_16x16x32_bf16(af[_i][0], bsrc[_j][0], _a, 0, 0, 0); \
      _a = __builtin_amdgcn_mfma_f32_16x16x32_bf16(af[_i][1], bsrc[_j][1], _a, 0, 0, 0); \
      acc[(mh) * 4 + _i][(nh) * 2 + _j] = _a;                                 \
    }                                                                         \
  __builtin_amdgcn_s_setprio(0);

  STG(BT, bn0, 0, 0, Bs[0]); STG(BT, bn0, 0, 1, Bs[0]);
  STG(A,  bm0, 0, 0, As[0]); STG(A,  bm0, 0, 1, As[0]);
  STG(BT, bn0, 1, 0, Bs[1]); STG(BT, bn0, 1, 1, Bs[1]);
  STG(A,  bm0, 1, 0, As[1]);
  VMW(6);
  BARX();

  short8 af[4][2], bf0[2][2], bf1[2][2];
  for (int j = 0; j < niter; ++j) {
    int t2 = 2 * j + 2; if (t2 >= ntiles) t2 -= ntiles;
    int t3 = t2 + 1;

    LDA4(As[0], 0); LDB2(Bs[0], 0, bf0);                 // ph1
    STG(A, bm0, 2 * j + 1, 1, As[1]);
    BARX(); LGKM0();
    MFQ(0, 0, bf0);
    BARX();

    LDB2(Bs[0], 1, bf1);                                 // ph2
    BARX(); LGKM0();
    MFQ(0, 1, bf1);
    BARX();

    LDA4(As[0], 1);                                      // ph3
    STG(BT, bn0, t2, 0, Bs[0]); STG(BT, bn0, t2, 1, Bs[0]);
    BARX(); LGKM0();
    MFQ(1, 1, bf1);
    BARX();

    STG(A, bm0, t2, 0, As[0]);                           // ph4
    VMW(6);
    BARX(); LGKM0();
    MFQ(1, 0, bf0);
    BARX();

    LDA4(As[1], 0); LDB2(Bs[1], 0, bf0);                 // ph5
    STG(A, bm0, t2, 1, As[0]);
    BARX(); LGKM0();
    MFQ(0, 0, bf0);
    BARX();

    LDB2(Bs[1], 1, bf1);                                 // ph6
    BARX(); LGKM0();
    MFQ(0, 1, bf1);
    BARX();

    LDA4(As[1], 1);                                      // ph7
    STG(BT, bn0, t3, 0, Bs[1]); STG(BT, bn0, t3, 1, Bs[1]);
    BARX(); LGKM0();
    MFQ(1, 1, bf1);
    BARX();

    STG(A, bm0, t3, 0, As[1]);                           // ph8
    VMW(6);
    BARX(); LGKM0();
    MFQ(1, 0, bf0);
    BARX();
  }
  asm volatile("s_waitcnt vmcnt(0)" ::: "memory");

#undef STG
#undef LDA4
#undef LDB2
#undef MFQ

#pragma unroll
  for (int i = 0; i < 8; ++i) {
    int r = bm0 + wm * 128 + i * 16 + qd * 4;
#pragma unroll
    for (int jj = 0; jj < 4; ++jj) {
      int c = bn0 + wn * 64 + jj * 16 + l;
#pragma unroll
      for (int reg = 0; reg < 4; ++reg) {
        if (OUT_MODE == 1)
          ((u16*)Cv)[(size_t)(r + reg) * N + c] = f2bf(acc[i][jj][reg]);
        else
          atomicAdd(&((float*)Cv)[(size_t)(r + reg) * N + c], acc[i][jj][reg]);
      }
    }
  }
}

// ---------------------------------------------------------------- rmsnorm
__global__ void k_rmsnorm(const float* __restrict__ in, int istride, int W,
                          const float* __restrict__ w, u16* __restrict__ out) {
  int row = blockIdx.x, tid = threadIdx.x;
  const float* x = in + (size_t)row * istride;
  float s = 0.f;
  for (int i = tid; i < W; i += 256) { float v = x[i]; s += v * v; }
#pragma unroll
  for (int o = 32; o; o >>= 1) s += __shfl_xor(s, o);
  __shared__ float red[4];
  if ((tid & 63) == 0) red[tid >> 6] = s;
  __syncthreads();
  float tot = red[0] + red[1] + red[2] + red[3];
  float sc = rsqrtf(tot / (float)W + 1e-6f);
  for (int i = tid; i < W; i += 256)
    out[(size_t)row * W + i] = f2bf(x[i] * sc * w[i]);
}

// ---------------------------------------------------------------- rope
__global__ void k_rope_q(u16* __restrict__ q) {   // in-place on (1024, 128*192)
  int idx = blockIdx.x * 256 + threadIdx.x;       // 1024*128*32
  int s = idx >> 12, r = idx & 4095, h = r >> 5, i = r & 31;
  float inv = expf((float)i * (-logf(10000.f) / 32.f));
  float ang = (float)s * inv, sn, cs;
  sincosf(ang, &sn, &cs);
  u16* p1 = q + (size_t)s * 24576 + h * 192 + 128 + i;
  u16* p2 = p1 + 32;
  float x1 = bf2f(*p1), x2 = bf2f(*p2);
  *p1 = f2bf(x1 * cs - x2 * sn);
  *p2 = f2bf(x2 * cs + x1 * sn);
}

__global__ void k_rope_k(const float* __restrict__ ckv, u16* __restrict__ kr) {
  int idx = blockIdx.x * 256 + threadIdx.x;       // 1024*32
  int s = idx >> 5, i = idx & 31;
  float inv = expf((float)i * (-logf(10000.f) / 32.f));
  float ang = (float)s * inv, sn, cs;
  sincosf(ang, &sn, &cs);
  const float* src = ckv + (size_t)s * 576 + 512;
  float x1 = src[i], x2 = src[i + 32];
  kr[s * 64 + i]      = f2bf(x1 * cs - x2 * sn);
  kr[s * 64 + 32 + i] = f2bf(x2 * cs + x1 * sn);
}

// ---------------------------------------------------------------- V transpose
__global__ void k_transpose_v(const u16* __restrict__ kv, u16* __restrict__ vt) {
  __shared__ u16 tile[32][33];
  int h = blockIdx.z, s0 = blockIdx.x * 32, d0 = blockIdx.y * 32;
  int tx = threadIdx.x, ty = threadIdx.y;   // 32 x 8
#pragma unroll
  for (int k2 = 0; k2 < 4; k2++) {
    int r = ty + k2 * 8;
    tile[r][tx] = kv[(size_t)(s0 + r) * 32768 + h * 256 + 128 + d0 + tx];
  }
  __syncthreads();
#pragma unroll
  for (int k2 = 0; k2 < 4; k2++) {
    int r = ty + k2 * 8;
    vt[(size_t)h * 131072 + (size_t)(d0 + r) * 1024 + s0 + tx] = tile[tx][r];
  }
}

// ---------------------------------------------------------------- attention
// One block = (head h, 64 q-rows). 4 waves x 16 q-rows. 16 kv-tiles of 64.
// Swapped-operand structure: QK computes S^T = mfma(K_frag, Q_frag) so each
// lane owns q-row (q = lane&15) with 16 in-register S values
// (k = j*16 + qd*4 + reg). Softmax: in-lane tree + shfl_xor(16,32); m/l scalar.
// PV B-operand P^T[k][q=l] assembled in-register: RNE-pack S pairs to bf16
// (kappa = k/2 = j*8 + qd*2 + t0), then ds_bpermute from lane
// l + 32*(qd&1) + 16*t1 picking register j = 2ks + (qd>>1) (cndmask on lane>=32):
// target u32 t of pf[ks] = P pairs k = ks*32 + qd*8 + 2t.
// PV: O^T = mfma(V_frag, pf) -> Of[jt][reg] = O^T[dv=jt*16+qd*4+reg][q=l].
// Epilogue: per-wave LDS transpose (reuses Ks, XOR-swizzled) -> coalesced store.
__global__ __launch_bounds__(256, 3) void k_attn(
    const u16* __restrict__ q,    // (1024, 128*192)
    const u16* __restrict__ kvn,  // (1024, 128*256): k_nope at h*256+0..127
    const u16* __restrict__ kr,   // (1024, 64) roped k_rope, shared across heads
    const u16* __restrict__ vt,   // (128, 128, 1024) V^T per head
    u16* __restrict__ o)          // (1024, 128*128)
{
  __shared__ u16 Ks[64][200];
  __shared__ u16 Vs[128][72];
  const int h = blockIdx.x, q0 = blockIdx.y * 64;
  const int tid = threadIdx.x, wave = tid >> 6, lane = tid & 63;
  const int qd = lane >> 4, l = lane & 15;
  const bool hi5 = lane >= 32;
  const int bidx0 = (l + ((lane >> 4) & 1) * 32) << 2;   // bpermute byte idx, t1=0
  const int bidx1 = bidx0 + 64;                          // t1=1
  const float scale = 0.07216878364870323f;   // 1/sqrt(192)
  const f32x4 fzero = {0.f, 0.f, 0.f, 0.f};

  short8 qf[6];
  {
    const u16* qp = q + (size_t)(q0 + wave * 16 + l) * 24576 + h * 192 + qd * 8;
#pragma unroll
    for (int kk = 0; kk < 6; kk++) qf[kk] = *(const short8*)(qp + kk * 32);
  }

  f32x4 Of[8];
#pragma unroll
  for (int jt = 0; jt < 8; jt++) Of[jt] = fzero;
  float m_i = -1e30f;
  float l_i = 0.f;

  for (int kt = 0; kt < 16; ++kt) {
    const int kv0 = kt * 64;
    __syncthreads();
#pragma unroll
    for (int it = 0; it < 6; ++it) {
      int ci = it * 256 + tid;
      int r = ci / 24, c = ci % 24;
      int col0 = c * 8;
      const u16* src = (col0 < 128)
          ? kvn + (size_t)(kv0 + r) * 32768 + h * 256 + col0
          : kr + (size_t)(kv0 + r) * 64 + (col0 - 128);
      *(short8*)&Ks[r][col0] = *(const short8*)src;
    }
#pragma unroll
    for (int it = 0; it < 4; ++it) {
      int ci = it * 256 + tid;
      int dv = ci >> 3, c = ci & 7;
      *(short8*)&Vs[dv][c * 8] =
          *(const short8*)(vt + (size_t)h * 131072 + (size_t)dv * 1024 + kv0 + c * 8);
    }
    __syncthreads();

    // S^T = K . Q^T : lane holds S[k = j*16+qd*4+reg][q = l]
    f32x4 sf[4];
#pragma unroll
    for (int j = 0; j < 4; j++) sf[j] = fzero;
    __builtin_amdgcn_s_setprio(1);
#pragma unroll
    for (int kk = 0; kk < 6; kk++)
#pragma unroll
      for (int j = 0; j < 4; j++) {
        short8 kf = *(const short8*)&Ks[j * 16 + l][kk * 32 + qd * 8];
        sf[j] = __builtin_amdgcn_mfma_f32_16x16x32_bf16(kf, qf[kk], sf[j], 0, 0, 0);
      }
    __builtin_amdgcn_s_setprio(0);
#pragma unroll
    for (int j = 0; j < 4; j++) sf[j] *= scale;

    // online softmax over k for this lane's q-row
    float mx0 = fmaxf(fmaxf(sf[0][0], sf[0][1]), fmaxf(sf[0][2], sf[0][3]));
    float mx1 = fmaxf(fmaxf(sf[1][0], sf[1][1]), fmaxf(sf[1][2], sf[1][3]));
    float mx2 = fmaxf(fmaxf(sf[2][0], sf[2][1]), fmaxf(sf[2][2], sf[2][3]));
    float mx3 = fmaxf(fmaxf(sf[3][0], sf[3][1]), fmaxf(sf[3][2], sf[3][3]));
    float mx = fmaxf(fmaxf(mx0, mx1), fmaxf(mx2, mx3));
    mx = fmaxf(mx, __shfl_xor(mx, 16));
    mx = fmaxf(mx, __shfl_xor(mx, 32));
    float mnew = fmaxf(m_i, mx);
    float alpha = expf(m_i - mnew);
    m_i = mnew;

    float rs = 0.f;
#pragma unroll
    for (int j = 0; j < 4; j++)
#pragma unroll
      for (int r = 0; r < 4; r++) {
        float p = expf(sf[j][r] - mnew);
        sf[j][r] = p;
        rs += p;
      }
    rs += __shfl_xor(rs, 16);
    rs += __shfl_xor(rs, 32);
    l_i = l_i * alpha + rs;
#pragma unroll
    for (int jt = 0; jt < 8; jt++) Of[jt] *= alpha;

    // pack P pairs: cv[j][t0] = bf16(k=j*16+qd*4+2*t0, +1)
    unsigned cv[4][2];
#pragma unroll
    for (int j = 0; j < 4; j++) {
      cv[j][0] = pk2(sf[j][0], sf[j][1]);
      cv[j][1] = pk2(sf[j][2], sf[j][3]);
    }

    // assemble P^T fragment + PV
#pragma unroll
    for (int ks = 0; ks < 2; ++ks) {
      union { unsigned u[4]; short8 v; } pfu;
#pragma unroll
      for (int t1 = 0; t1 < 2; ++t1) {
        const int bidx = t1 ? bidx1 : bidx0;
#pragma unroll
        for (int t0 = 0; t0 < 2; ++t0) {
          int pa = __builtin_amdgcn_ds_bpermute(bidx, (int)cv[2 * ks][t0]);
          int pb = __builtin_amdgcn_ds_bpermute(bidx, (int)cv[2 * ks + 1][t0]);
          pfu.u[t1 * 2 + t0] = (unsigned)(hi5 ? pb : pa);
        }
      }
      __builtin_amdgcn_s_setprio(1);
#pragma unroll
      for (int jt = 0; jt < 8; jt++) {
        short8 vf = *(const short8*)&Vs[jt * 16 + l][ks * 32 + qd * 8];
        Of[jt] = __builtin_amdgcn_mfma_f32_16x16x32_bf16(vf, pfu.v, Of[jt], 0, 0, 0);
      }
      __builtin_amdgcn_s_setprio(0);
    }
  }

  // epilogue: O^T -> O via per-wave LDS transpose (reuse Ks region)
  __syncthreads();   // all waves done reading Ks/Vs
  float inv_l = 1.f / l_i;
  u16* Ot = ((u16*)Ks) + wave * 2048;   // 16 q-rows x 128 dv (u16)
#pragma unroll
  for (int jt = 0; jt < 8; jt++)
#pragma unroll
    for (int reg = 0; reg < 4; ++reg) {
      int slot = jt * 2 + (qd >> 1);            // dv>>3
      int off  = (qd & 1) * 4 + reg;            // dv&7
      int ps   = (slot & 8) | ((slot & 7) ^ (l & 7));
      Ot[l * 128 + ps * 8 + off] = f2bf(Of[jt][reg] * inv_l);
    }
  // wave-local region: no barrier needed (lgkmcnt ordering suffices)
#pragma unroll
  for (int it = 0; it < 4; ++it) {
    int idx = it * 64 + lane;
    int qq = idx >> 4, g = idx & 15;
    int ps = (g & 8) | ((g & 7) ^ (qq & 7));
    short8 v = *(const short8*)&Ot[qq * 128 + ps * 8];
    *(short8*)&o[(size_t)(q0 + wave * 16 + qq) * 16384 + h * 128 + g * 8] = v;
  }
}

// ---------------------------------------------------------------- launch
extern "C" void kernel_launch(void* const* d_in, const int* in_sizes, int n_in,
                              void* d_out, int out_size, void* d_ws, size_t ws_size,
                              hipStream_t stream)
{
  const float* hidden = (const float*)d_in[0];
  const float* Wq_c   = (const float*)d_in[1];
  const float* q_nw   = (const float*)d_in[2];
  const float* Wq_d   = (const float*)d_in[3];
  const float* Wkv_c  = (const float*)d_in[4];
  const float* kv_nw  = (const float*)d_in[5];
  const float* Wkv_d  = (const float*)d_in[6];
  const float* Wo     = (const float*)d_in[7];

  float* out = (float*)d_out;                       // (1024, 5120)
  float* ckv = out + (size_t)1024 * 5120;           // (1024, 576)  output #2

  char* ws = (char*)d_ws;
  u16*   h_bf  = (u16*)ws;   ws += (size_t)1024 * 5120 * 2;
  float* q_c   = (float*)ws; ws += (size_t)1024 * 1536 * 4;
  u16*   q_n   = (u16*)ws;   ws += (size_t)1024 * 1536 * 2;
  u16*   qbuf  = (u16*)ws;   ws += (size_t)1024 * 24576 * 2;
  u16*   kv_n  = (u16*)ws;   ws += (size_t)1024 * 512 * 2;
  u16*   kvbuf = (u16*)ws;   ws += (size_t)1024 * 32768 * 2;
  u16*   krope = (u16*)ws;   ws += (size_t)1024 * 64 * 2;
  u16*   vt    = (u16*)ws;   ws += (size_t)128 * 128 * 1024 * 2;
  u16*   attno = (u16*)ws;   ws += (size_t)1024 * 16384 * 2;
  // transposed bf16 weights [Npad][K]:
  u16*   wtqc  = (u16*)ws;   ws += (size_t)1536 * 5120 * 2;
  u16*   wtkvc = (u16*)ws;   ws += (size_t)640 * 5120 * 2;
  u16*   wtqd  = (u16*)ws;   ws += (size_t)24576 * 1536 * 2;
  u16*   wtkvd = (u16*)ws;   ws += (size_t)32768 * 512 * 2;
  u16*   wto   = (u16*)ws;   ws += (size_t)5120 * 16384 * 2;

  dim3 b256(256), b512(512), bwt(32, 8);

  // zero atomic-accumulated outputs: d_out (out+ckv) and q_c
  k_zero<<<5696, b256, 0, stream>>>(out, (1024 * 5120 + 1024 * 576) / 4);
  k_zero<<<1536, b256, 0, stream>>>(q_c, 1024 * 1536 / 4);

  // weight cast+transpose
  k_wt<<<dim3(48, 160),  bwt, 0, stream>>>(Wq_c,  wtqc,  5120, 1536);
  k_wt<<<dim3(20, 160),  bwt, 0, stream>>>(Wkv_c, wtkvc, 5120, 576);
  k_wt<<<dim3(768, 48),  bwt, 0, stream>>>(Wq_d,  wtqd,  1536, 24576);
  k_wt<<<dim3(1024, 16), bwt, 0, stream>>>(Wkv_d, wtkvd, 512,  32768);
  k_wt<<<dim3(160, 512), bwt, 0, stream>>>(Wo,    wto,   16384, 5120);

  k_cast<<<5120, b256, 0, stream>>>(hidden, h_bf, 1024 * 5120 / 4);

  // q-down (split-K x4) and kv-down (split-K x8), fp32 atomic accumulate
  k_gemm_bt<2><<<dim3(12, 8, 4), b256, 0, stream>>>(h_bf, wtqc,  q_c, 1024, 1536, 5120, 1280);
  k_gemm_bt<2><<<dim3(5, 8, 8),  b256, 0, stream>>>(h_bf, wtkvc, ckv, 1024, 576,  5120, 640);

  k_rmsnorm<<<1024, b256, 0, stream>>>(q_c, 1536, 1536, q_nw, q_n);
  k_rmsnorm<<<1024, b256, 0, stream>>>(ckv, 576,  512,  kv_nw, kv_n);

  // up-projections: 256^2 8-phase, bf16 out
  k_gemm256<1><<<dim3(96, 4, 1),  b512, 0, stream>>>(q_n,  wtqd,  qbuf,  1024, 24576, 1536, 1536);
  k_gemm256<1><<<dim3(128, 4, 1), b512, 0, stream>>>(kv_n, wtkvd, kvbuf, 1024, 32768, 512,  512);

  k_rope_q<<<16384, b256, 0, stream>>>(qbuf);
  k_rope_k<<<128,   b256, 0, stream>>>(ckv, krope);

  k_transpose_v<<<dim3(32, 4, 128), dim3(32, 8), 0, stream>>>(kvbuf, vt);

  k_attn<<<dim3(128, 16), b256, 0, stream>>>(qbuf, kvbuf, krope, vt, attno);

  // out-proj: 256^2 8-phase, split-K x3 uneven (86/86/84 K-tiles) -> 240 blocks
  k_gemm256<2><<<dim3(20, 4, 3), b512, 0, stream>>>(attno, wto, out, 1024, 5120, 16384, 5504);
}